// Round 5
// baseline (229.739 us; speedup 1.0000x reference)
//
#include <hip/hip_runtime.h>
#include <hip/hip_bf16.h>

#define B_SZ 8192
#define D_SZ 1024   // elements; == bytes in fp8

typedef __attribute__((ext_vector_type(4))) float floatx4;
typedef __attribute__((ext_vector_type(8))) int   int8v;
typedef __attribute__((ext_vector_type(4))) int   int4v;

__device__ __forceinline__ void glds16(const void* g, void* l) {
    __builtin_amdgcn_global_load_lds(
        (const __attribute__((address_space(1))) void*)g,
        (__attribute__((address_space(3))) void*)l, 16, 0, 0);
}

// One wave per row (rows 0..8191 = img, 8192..16383 = txt). 4 rows/block.
// Also zero-initializes the output accumulator (stream order guarantees this
// lands before the GEMM's atomics; done every call, re-poison safe).
__global__ __launch_bounds__(256) void norm_cast_fp8(
    const float* __restrict__ img, const float* __restrict__ txt,
    unsigned char* __restrict__ imgQ, unsigned char* __restrict__ txtQ,
    float* __restrict__ out)
{
    if (blockIdx.x == 0 && threadIdx.x == 0) *out = 0.0f;

    const int lane = threadIdx.x & 63;
    int w = blockIdx.x * 4 + (threadIdx.x >> 6);
    const float* src; unsigned char* dst;
    if (w < B_SZ) { src = img + (size_t)w * D_SZ; dst = imgQ + (size_t)w * D_SZ; }
    else { w -= B_SZ; src = txt + (size_t)w * D_SZ; dst = txtQ + (size_t)w * D_SZ; }

    float4 v[4];
    float ss = 0.0f;
    #pragma unroll
    for (int i = 0; i < 4; ++i) {
        v[i] = ((const float4*)src)[lane + 64 * i];
        ss += v[i].x*v[i].x + v[i].y*v[i].y + v[i].z*v[i].z + v[i].w*v[i].w;
    }
    #pragma unroll
    for (int off = 1; off < 64; off <<= 1) ss += __shfl_xor(ss, off, 64);
    const float scale = 1.0f / fmaxf(sqrtf(ss), 1e-12f);

    #pragma unroll
    for (int i = 0; i < 4; ++i) {
        int packed = 0;
        packed = __builtin_amdgcn_cvt_pk_fp8_f32(v[i].x * scale, v[i].y * scale, packed, false);
        packed = __builtin_amdgcn_cvt_pk_fp8_f32(v[i].z * scale, v[i].w * scale, packed, true);
        ((int*)dst)[lane + 64 * i] = packed;
    }
}

// Fused MX-fp8 GEMM (A @ B^T) + SigLIP loss. Block tile 256x128, 4 waves in
// 2x2, wave tile 128x64 (8mt x 4nt of 16x16x128 scaled-MFMA, scales = 1.0).
// BK=128 -> 8 K-iters, 32 MFMAs per barrier pair.
//
// LDS: 64-B-row lo/hi arrays (R2's conflict-free geometry; granule at
// logical g sits at physical p = g ^ ((row>>1)&3), swizzle applied on the
// GLOBAL side of global_load_lds so LDS slots stay wave-contiguous).
// A (32 KB/tile) is DOUBLE-buffered; B (16 KB) single-buffered: B-fragments
// (32 VGPR) are pulled into registers before barrier(B) licenses the Bs
// overwrite, while A-fragments stream from the safe buffer interleaved with
// the MFMAs. Total 80 KB LDS -> 2 blocks/CU; ~100 VGPR + 128 acc.
__global__ __launch_bounds__(256, 2) void siglip_gemm_loss_fp8(
    const unsigned char* __restrict__ A,   // imgQ [B,D] e4m3
    const unsigned char* __restrict__ Bt,  // txtQ [B,D] e4m3
    const float* __restrict__ tp, const float* __restrict__ bp,
    float* __restrict__ out)
{
    __shared__ __align__(16) unsigned char As[2][2][256 * 64]; // [buf][lo/hi] 64 KB
    __shared__ __align__(16) unsigned char Bs[2][128 * 64];    // [lo/hi]      16 KB

    const int tid  = threadIdx.x;
    const int lane = tid & 63;
    const int wave = tid >> 6;
    const int wm = wave & 1, wn = wave >> 1;
    const int bi = blockIdx.x * 256;
    const int bj = blockIdx.y * 128;
    const int quad = lane >> 4;   // 0..3 -> 32-byte K-chunk
    const int l16  = lane & 15;

    floatx4 acc[8][4];
    #pragma unroll
    for (int i = 0; i < 8; ++i)
        #pragma unroll
        for (int j = 0; j < 4; ++j)
            acc[i][j] = (floatx4){0.f, 0.f, 0.f, 0.f};

    // A: 1024 slots per half-array (row = s>>2, phys p = s&3, g = p^((row>>1)&3))
    auto stage_a = [&](int k0, int buf) {
        #pragma unroll
        for (int it = 0; it < 4; ++it) {
            int s = tid + it * 256;
            int row = s >> 2, p = s & 3;
            int g = p ^ ((row >> 1) & 3);
            const unsigned char* ga = A + ((size_t)(bi + row) * D_SZ + k0 + g * 16);
            glds16(ga,      As[buf][0] + s * 16);
            glds16(ga + 64, As[buf][1] + s * 16);
        }
    };
    // B: 512 slots per half-array
    auto stage_b = [&](int k0) {
        #pragma unroll
        for (int it = 0; it < 2; ++it) {
            int s = tid + it * 256;
            int row = s >> 2, p = s & 3;
            int g = p ^ ((row >> 1) & 3);
            const unsigned char* gb = Bt + ((size_t)(bj + row) * D_SZ + k0 + g * 16);
            glds16(gb,      Bs[0] + s * 16);
            glds16(gb + 64, Bs[1] + s * 16);
        }
    };

    // fragment geometry (proven in R2/R4): array = quad>>1, granule pair
    // (quad&1)*2 + {0,1}, physical pos XOR'd by (l16>>1)&3
    const int sw   = (l16 >> 1) & 3;
    const int hsel = quad >> 1;
    const int p0   = ((quad & 1) * 2) ^ sw;
    const int p1   = p0 ^ 1;

    stage_a(0, 0);
    stage_b(0);

    for (int kk = 0; kk < D_SZ / 128; ++kk) {
        __syncthreads();   // (A) per-wave vmcnt drained before barrier => all DMA visible
        const int buf = kk & 1;

        int8v bfr[4];
        #pragma unroll
        for (int nt = 0; nt < 4; ++nt) {
            int r = wn * 64 + nt * 16 + l16;
            int4v lo = *(const int4v*)(Bs[hsel] + r * 64 + p0 * 16);
            int4v hi = *(const int4v*)(Bs[hsel] + r * 64 + p1 * 16);
            bfr[nt][0]=lo[0]; bfr[nt][1]=lo[1]; bfr[nt][2]=lo[2]; bfr[nt][3]=lo[3];
            bfr[nt][4]=hi[0]; bfr[nt][5]=hi[1]; bfr[nt][6]=hi[2]; bfr[nt][7]=hi[3];
        }
        __syncthreads();   // (B) all waves consumed Bs -> overwrite licensed

        if (kk + 1 < D_SZ / 128) {
            stage_a((kk + 1) * 128, buf ^ 1);   // other A buffer: no race w/ reads below
            stage_b((kk + 1) * 128);            // Bs consumed above
        }

        #pragma unroll
        for (int mt = 0; mt < 8; ++mt) {
            int r = wm * 128 + mt * 16 + l16;
            int4v lo = *(const int4v*)(As[buf][hsel] + r * 64 + p0 * 16);
            int4v hi = *(const int4v*)(As[buf][hsel] + r * 64 + p1 * 16);
            int8v af;
            af[0]=lo[0]; af[1]=lo[1]; af[2]=lo[2]; af[3]=lo[3];
            af[4]=hi[0]; af[5]=hi[1]; af[6]=hi[2]; af[7]=hi[3];
            #pragma unroll
            for (int nt = 0; nt < 4; ++nt)
                acc[mt][nt] = __builtin_amdgcn_mfma_scale_f32_16x16x128_f8f6f4(
                    af, bfr[nt], acc[mt][nt],
                    0, 0,          // cbsz=fp8, blgp=fp8
                    0, 127,        // scale A: E8M0 127 = 1.0
                    0, 127);       // scale B
        }
    }

    // Epilogue: softplus(-label*logit) with hw exp/log, reduce.
    const float t    = fminf(__expf(tp[0]), 100.0f);
    const float bias = bp[0];
    float lsum = 0.0f;
    #pragma unroll
    for (int mt = 0; mt < 8; ++mt) {
        #pragma unroll
        for (int nt = 0; nt < 4; ++nt) {
            const int jj = bj + wn * 64 + nt * 16 + l16;               // C/D col
            #pragma unroll
            for (int r = 0; r < 4; ++r) {
                const int ii = bi + wm * 128 + mt * 16 + quad * 4 + r; // C/D row
                float logit = fmaf(acc[mt][nt][r], t, bias);
                float z = (ii == jj) ? logit : -logit;
                float e = __expf(-fabsf(z));
                lsum += fmaxf(-z, 0.0f) + __logf(1.0f + e);
            }
        }
    }
    #pragma unroll
    for (int off = 32; off > 0; off >>= 1) lsum += __shfl_down(lsum, off, 64);

    __shared__ float red[4];
    if (lane == 0) red[wave] = lsum;
    __syncthreads();
    if (tid == 0)
        atomicAdd(out, (red[0] + red[1] + red[2] + red[3]) * (1.0f / (float)B_SZ));
}

extern "C" void kernel_launch(void* const* d_in, const int* in_sizes, int n_in,
                              void* d_out, int out_size, void* d_ws, size_t ws_size,
                              hipStream_t stream) {
    const float* img = (const float*)d_in[0];
    const float* txt = (const float*)d_in[1];
    const float* tp  = (const float*)d_in[2];
    const float* bp  = (const float*)d_in[3];
    float* out = (float*)d_out;

    unsigned char* imgQ = (unsigned char*)d_ws;                   // 8 MB
    unsigned char* txtQ = imgQ + (size_t)B_SZ * D_SZ;             // 8 MB

    norm_cast_fp8<<<(2 * B_SZ) / 4, 256, 0, stream>>>(img, txt, imgQ, txtQ, out);
    dim3 grid(B_SZ / 256, B_SZ / 128);
    siglip_gemm_loss_fp8<<<grid, 256, 0, stream>>>(imgQ, txtQ, tp, bp, out);
}